// Round 2
// baseline (105.695 us; speedup 1.0000x reference)
//
#include <hip/hip_runtime.h>

#define N_SAMPLES 8192
#define DIM 64
#define NUM_CLASSES 20
#define MARGIN 1.0f

// ws layout: [0..19] float class_max, [20..39] int class_count  (160 bytes)

// Kernel 1: per-sample squared distance to its OWN class embedding,
// then per-class max (atomicMax on float bits, valid since all values >= 0)
// and per-class count.
__global__ __launch_bounds__(256) void triplet_dist_kernel(
    const float* __restrict__ emb,      // [N_SAMPLES, DIM]
    const int* __restrict__ labels,     // [N_SAMPLES]
    const float* __restrict__ lemb,     // [NUM_CLASSES, DIM]
    float* __restrict__ cls_max,        // [NUM_CLASSES]
    int* __restrict__ cls_cnt)          // [NUM_CLASSES]
{
    __shared__ float s_lemb[NUM_CLASSES * DIM];  // 5 KB
    const int tid = threadIdx.x;

    // Cooperative load of all label embeddings (1280 floats) into LDS.
    for (int i = tid; i < NUM_CLASSES * DIM; i += 256)
        s_lemb[i] = lemb[i];
    __syncthreads();

    // 16 lanes per sample: each lane reads one float4 (16 lanes * 16B = 256B
    // per sample, perfectly coalesced across the wave).
    const int sample = blockIdx.x * 16 + (tid >> 4);
    const int lane16 = tid & 15;

    if (sample < N_SAMPLES) {
        const int c = labels[sample];
        const float4 e = *reinterpret_cast<const float4*>(emb + sample * DIM + lane16 * 4);
        const float4 l = *reinterpret_cast<const float4*>(&s_lemb[c * DIM + lane16 * 4]);
        const float d0 = e.x - l.x;
        const float d1 = e.y - l.y;
        const float d2 = e.z - l.z;
        const float d3 = e.w - l.w;
        float part = d0 * d0 + d1 * d1 + d2 * d2 + d3 * d3;

        // Reduce across the 16 lanes of this sample (xor masks < 16 stay
        // within the 16-lane group; wave = 64 on gfx950).
        part += __shfl_xor(part, 1);
        part += __shfl_xor(part, 2);
        part += __shfl_xor(part, 4);
        part += __shfl_xor(part, 8);

        if (lane16 == 0) {
            // part >= 0, so integer compare on float bits is order-preserving.
            atomicMax(reinterpret_cast<int*>(&cls_max[c]), __float_as_int(part));
            atomicAdd(&cls_cnt[c], 1);
        }
    }
}

// Kernel 2: loss = sum_c count(c) * max(c) + N * MARGIN
__global__ __launch_bounds__(64) void triplet_finalize_kernel(
    const float* __restrict__ cls_max,
    const int* __restrict__ cls_cnt,
    float* __restrict__ out)
{
    const int t = threadIdx.x;
    float v = 0.0f;
    if (t < NUM_CLASSES)
        v = cls_max[t] * static_cast<float>(cls_cnt[t]);
    // Full-wave (64-lane) reduction.
    v += __shfl_xor(v, 1);
    v += __shfl_xor(v, 2);
    v += __shfl_xor(v, 4);
    v += __shfl_xor(v, 8);
    v += __shfl_xor(v, 16);
    v += __shfl_xor(v, 32);
    if (t == 0)
        out[0] = v + static_cast<float>(N_SAMPLES) * MARGIN;
}

extern "C" void kernel_launch(void* const* d_in, const int* in_sizes, int n_in,
                              void* d_out, int out_size, void* d_ws, size_t ws_size,
                              hipStream_t stream) {
    const float* emb    = static_cast<const float*>(d_in[0]);  // [8192, 64] f32
    const int*   labels = static_cast<const int*>(d_in[1]);    // [8192] int
    const float* lemb   = static_cast<const float*>(d_in[2]);  // [20, 64] f32
    float* out = static_cast<float*>(d_out);

    float* cls_max = static_cast<float*>(d_ws);
    int*   cls_cnt = reinterpret_cast<int*>(static_cast<char*>(d_ws) + NUM_CLASSES * sizeof(float));

    // Zero the class max/count scratch (ws is re-poisoned to 0xAA each call).
    hipMemsetAsync(d_ws, 0, NUM_CLASSES * (sizeof(float) + sizeof(int)), stream);

    triplet_dist_kernel<<<N_SAMPLES / 16, 256, 0, stream>>>(
        emb, labels, lemb, cls_max, cls_cnt);

    triplet_finalize_kernel<<<1, 64, 0, stream>>>(cls_max, cls_cnt, out);
}

// Round 3
// 62.166 us; speedup vs baseline: 1.7002x; 1.7002x over previous
//
#include <hip/hip_runtime.h>

#define N_SAMPLES 8192
#define DIM 64
#define NUM_CLASSES 20
#define MARGIN 1.0f
#define NB 128   // blocks in kernel 1

// ws layout: pmax[NUM_CLASSES][NB] (int: float bits), then pcnt[NUM_CLASSES][NB] (int)
// Every slot is written unconditionally by kernel 1 -> no memset needed.

// Kernel 1: per-sample squared distance to its OWN class embedding,
// accumulated into a per-block LDS histogram (max + count per class),
// then plain stores of the 20 partials per block. Zero global atomics.
__global__ __launch_bounds__(256) void triplet_dist_kernel(
    const float* __restrict__ emb,      // [N_SAMPLES, DIM]
    const int* __restrict__ labels,     // [N_SAMPLES]
    const float* __restrict__ lemb,     // [NUM_CLASSES, DIM]
    int* __restrict__ pmax,             // [NUM_CLASSES * NB] float-bits
    int* __restrict__ pcnt)             // [NUM_CLASSES * NB]
{
    __shared__ float s_lemb[NUM_CLASSES * DIM];  // 5 KB
    __shared__ int s_max[NUM_CLASSES];
    __shared__ int s_cnt[NUM_CLASSES];
    const int tid = threadIdx.x;

    for (int i = tid; i < NUM_CLASSES * DIM; i += 256)
        s_lemb[i] = lemb[i];
    if (tid < NUM_CLASSES) { s_max[tid] = 0; s_cnt[tid] = 0; }
    __syncthreads();

    const int lane16 = tid & 15;
    // 16 lanes per sample, grid-stride: NB*16 = 2048 samples per sweep, 4 sweeps.
    for (int sample = blockIdx.x * 16 + (tid >> 4); sample < N_SAMPLES;
         sample += NB * 16) {
        const int c = labels[sample];
        const float4 e = *reinterpret_cast<const float4*>(emb + sample * DIM + lane16 * 4);
        const float4 l = *reinterpret_cast<const float4*>(&s_lemb[c * DIM + lane16 * 4]);
        const float d0 = e.x - l.x;
        const float d1 = e.y - l.y;
        const float d2 = e.z - l.z;
        const float d3 = e.w - l.w;
        float part = d0 * d0 + d1 * d1 + d2 * d2 + d3 * d3;

        part += __shfl_xor(part, 1);
        part += __shfl_xor(part, 2);
        part += __shfl_xor(part, 4);
        part += __shfl_xor(part, 8);

        if (lane16 == 0) {
            // part >= 0 -> int compare on float bits is order-preserving.
            // LDS atomics: cheap, contention confined to this block.
            atomicMax(&s_max[c], __float_as_int(part));
            atomicAdd(&s_cnt[c], 1);
        }
    }
    __syncthreads();

    if (tid < NUM_CLASSES) {
        pmax[tid * NB + blockIdx.x] = s_max[tid];
        pcnt[tid * NB + blockIdx.x] = s_cnt[tid];
    }
}

// Kernel 2: reduce 128 partials per class; loss = sum_c cnt(c)*max(c) + N*MARGIN.
__global__ __launch_bounds__(256) void triplet_finalize_kernel(
    const int* __restrict__ pmax,
    const int* __restrict__ pcnt,
    float* __restrict__ out)
{
    __shared__ float s_val[NUM_CLASSES];
    const int t = threadIdx.x;

    if (t < NUM_CLASSES * 8) {          // 8 threads per class (8 | 64: no wave straddle)
        const int c = t >> 3;
        const int j = t & 7;
        int m = 0, cnt = 0;
        #pragma unroll
        for (int k = 0; k < NB / 8; ++k) {
            const int b = j + 8 * k;
            m = max(m, pmax[c * NB + b]);
            cnt += pcnt[c * NB + b];
        }
        m = max(m, __shfl_xor(m, 1)); cnt += __shfl_xor(cnt, 1);
        m = max(m, __shfl_xor(m, 2)); cnt += __shfl_xor(cnt, 2);
        m = max(m, __shfl_xor(m, 4)); cnt += __shfl_xor(cnt, 4);
        if (j == 0)
            s_val[c] = __int_as_float(m) * static_cast<float>(cnt);
    }
    __syncthreads();

    if (t == 0) {
        float s = 0.0f;
        #pragma unroll
        for (int c = 0; c < NUM_CLASSES; ++c) s += s_val[c];
        out[0] = s + static_cast<float>(N_SAMPLES) * MARGIN;
    }
}

extern "C" void kernel_launch(void* const* d_in, const int* in_sizes, int n_in,
                              void* d_out, int out_size, void* d_ws, size_t ws_size,
                              hipStream_t stream) {
    const float* emb    = static_cast<const float*>(d_in[0]);  // [8192, 64] f32
    const int*   labels = static_cast<const int*>(d_in[1]);    // [8192] int
    const float* lemb   = static_cast<const float*>(d_in[2]);  // [20, 64] f32
    float* out = static_cast<float*>(d_out);

    int* pmax = static_cast<int*>(d_ws);
    int* pcnt = pmax + NUM_CLASSES * NB;

    triplet_dist_kernel<<<NB, 256, 0, stream>>>(emb, labels, lemb, pmax, pcnt);
    triplet_finalize_kernel<<<1, 256, 0, stream>>>(pmax, pcnt, out);
}

// Round 4
// 61.788 us; speedup vs baseline: 1.7106x; 1.0061x over previous
//
#include <hip/hip_runtime.h>

#define N_SAMPLES 8192
#define DIM 64
#define NUM_CLASSES 20
#define MARGIN 1.0f
#define NBLK 512   // blocks in kernel 1; 16 samples per block, single sweep

// ws layout: pmax[NUM_CLASSES][NBLK] (int: float bits), then pcnt[NUM_CLASSES][NBLK].
// Every slot is written unconditionally by kernel 1 -> no init needed.

// Kernel 1: per-sample squared distance to its OWN class embedding,
// per-block LDS histogram (max + count per class), plain partial stores.
// No global atomics, no lemb staging (20x256B rows stay L1/L2-hot).
__global__ __launch_bounds__(256) void triplet_dist_kernel(
    const float* __restrict__ emb,      // [N_SAMPLES, DIM]
    const int* __restrict__ labels,     // [N_SAMPLES]
    const float* __restrict__ lemb,     // [NUM_CLASSES, DIM]
    int* __restrict__ pmax,             // [NUM_CLASSES * NBLK] float-bits
    int* __restrict__ pcnt)             // [NUM_CLASSES * NBLK]
{
    __shared__ int s_max[NUM_CLASSES];
    __shared__ int s_cnt[NUM_CLASSES];
    const int tid = threadIdx.x;

    if (tid < NUM_CLASSES) { s_max[tid] = 0; s_cnt[tid] = 0; }
    __syncthreads();

    // 16 lanes per sample; 16 samples per block; 512 blocks cover all 8192.
    const int sample = blockIdx.x * 16 + (tid >> 4);
    const int lane16 = tid & 15;

    const int c = labels[sample];
    const float4 e = *reinterpret_cast<const float4*>(emb + sample * DIM + lane16 * 4);
    const float4 l = *reinterpret_cast<const float4*>(lemb + c * DIM + lane16 * 4);
    const float d0 = e.x - l.x;
    const float d1 = e.y - l.y;
    const float d2 = e.z - l.z;
    const float d3 = e.w - l.w;
    float part = d0 * d0 + d1 * d1 + d2 * d2 + d3 * d3;

    // Reduce across the 16 lanes of this sample (wave = 64; masks < 16 stay in-group).
    part += __shfl_xor(part, 1);
    part += __shfl_xor(part, 2);
    part += __shfl_xor(part, 4);
    part += __shfl_xor(part, 8);

    if (lane16 == 0) {
        // part >= 0 -> int compare on float bits is order-preserving.
        atomicMax(&s_max[c], __float_as_int(part));
        atomicAdd(&s_cnt[c], 1);
    }
    __syncthreads();

    if (tid < NUM_CLASSES) {
        pmax[tid * NBLK + blockIdx.x] = s_max[tid];
        pcnt[tid * NBLK + blockIdx.x] = s_cnt[tid];
    }
}

// Kernel 2: reduce NBLK partials per class; loss = sum_c cnt(c)*max(c) + N*MARGIN.
// 16 threads per class, int4 (coalesced) partial loads, shuffle tree.
__global__ __launch_bounds__(320) void triplet_finalize_kernel(
    const int* __restrict__ pmax,
    const int* __restrict__ pcnt,
    float* __restrict__ out)
{
    __shared__ float s_val[NUM_CLASSES];
    const int t = threadIdx.x;

    if (t < NUM_CLASSES * 16) {         // 16 | 64: groups never straddle a wave
        const int c = t >> 4;
        const int j = t & 15;
        const int4* pm = reinterpret_cast<const int4*>(pmax + c * NBLK + j * 32);
        const int4* pc = reinterpret_cast<const int4*>(pcnt + c * NBLK + j * 32);
        int m = 0, cnt = 0;
        #pragma unroll
        for (int k = 0; k < 8; ++k) {   // 8 x int4 = 32 partials per thread
            const int4 v = pm[k];
            m = max(m, max(max(v.x, v.y), max(v.z, v.w)));
            const int4 w = pc[k];
            cnt += w.x + w.y + w.z + w.w;
        }
        m = max(m, __shfl_xor(m, 1)); cnt += __shfl_xor(cnt, 1);
        m = max(m, __shfl_xor(m, 2)); cnt += __shfl_xor(cnt, 2);
        m = max(m, __shfl_xor(m, 4)); cnt += __shfl_xor(cnt, 4);
        m = max(m, __shfl_xor(m, 8)); cnt += __shfl_xor(cnt, 8);
        if (j == 0)
            s_val[c] = __int_as_float(m) * static_cast<float>(cnt);
    }
    __syncthreads();

    if (t == 0) {
        float s = 0.0f;
        #pragma unroll
        for (int c = 0; c < NUM_CLASSES; ++c) s += s_val[c];
        out[0] = s + static_cast<float>(N_SAMPLES) * MARGIN;
    }
}

extern "C" void kernel_launch(void* const* d_in, const int* in_sizes, int n_in,
                              void* d_out, int out_size, void* d_ws, size_t ws_size,
                              hipStream_t stream) {
    const float* emb    = static_cast<const float*>(d_in[0]);  // [8192, 64] f32
    const int*   labels = static_cast<const int*>(d_in[1]);    // [8192] int
    const float* lemb   = static_cast<const float*>(d_in[2]);  // [20, 64] f32
    float* out = static_cast<float*>(d_out);

    int* pmax = static_cast<int*>(d_ws);
    int* pcnt = pmax + NUM_CLASSES * NBLK;

    triplet_dist_kernel<<<NBLK, 256, 0, stream>>>(emb, labels, lemb, pmax, pcnt);
    triplet_finalize_kernel<<<1, 320, 0, stream>>>(pmax, pcnt, out);
}